// Round 1
// baseline (9801.105 us; speedup 1.0000x reference)
//
#include <hip/hip_runtime.h>

// ============================================================================
// MMAEKNN: MLP autoencoder fwd + rec_loss + KNN(15) loss, bf16 MFMA pipeline.
//
// Pipeline:
//   1) x f32 -> bf16 ; weights f32 [K][N] -> bf16 [N][K] (transposed so every
//      GEMM is NT: both operands row-major along K, identical LDS staging).
//   2) 6x MFMA GEMM (16x16x32 bf16, 128x128 tile, global_load_lds width=16,
//      m97-style 2-barrier K loop). GEMM6 fuses rec_loss reduction.
//   3) gram_topk: Gram(x_bf16) 8192x8192 K=1024 fused with streaming per-row
//      top-15 (j split 8-way across blocks), then merge partials.
//   4) mask = knn | knn^T as 8192x8192 bitmask; gather set bits -> pair list;
//      per-pair z-dist (f32 z) + x-dist lookup from top-k values; max-reduce;
//      normalized squared-diff mean.
// ============================================================================

typedef __attribute__((ext_vector_type(8))) short bf16x8;
typedef __attribute__((ext_vector_type(4))) float f32x4;

#define DEVINL static __device__ __forceinline__

DEVINL unsigned short f2bf(float f){
  unsigned u = __float_as_uint(f);
  u += 0x7FFFu + ((u >> 16) & 1u);              // round-to-nearest-even
  return (unsigned short)(u >> 16);
}

DEVINL void gload16(const unsigned short* g, void* lds){
  __builtin_amdgcn_global_load_lds(
      (const __attribute__((address_space(1))) unsigned int*)g,
      (__attribute__((address_space(3))) unsigned int*)lds, 16, 0, 0);
}

// ---------------------------------------------------------------------------
__global__ __launch_bounds__(256) void cvt_f32_bf16_k(const float* __restrict__ in,
                                                      unsigned short* __restrict__ out, int n4){
  int i = blockIdx.x * 256 + threadIdx.x;
  if (i >= n4) return;
  float4 v = ((const float4*)in)[i];
  ushort4 o;
  o.x = f2bf(v.x); o.y = f2bf(v.y); o.z = f2bf(v.z); o.w = f2bf(v.w);
  ((ushort4*)out)[i] = o;
}

// w[K][N] f32 -> wt[N][K] bf16 (all dims multiples of 32)
__global__ void transpose_cvt_k(const float* __restrict__ w, unsigned short* __restrict__ wt,
                                int K, int N){
  __shared__ float t[32][33];
  int n0 = blockIdx.x << 5, k0 = blockIdx.y << 5;
  int tx = threadIdx.x, ty = threadIdx.y;
  t[ty][tx] = w[(size_t)(k0 + ty) * N + n0 + tx];
  __syncthreads();
  wt[(size_t)(n0 + ty) * K + k0 + tx] = f2bf(t[tx][ty]);
}

// row sums of squares (f32), one wave per row
__global__ __launch_bounds__(256) void rowsq_k(const float* __restrict__ x,
                                               float* __restrict__ sq, int ld){
  int lane = threadIdx.x & 63, wid = threadIdx.x >> 6;
  int row = blockIdx.x * 4 + wid;
  const float* p = x + (size_t)row * ld;
  float s = 0.f;
  for (int c = lane; c < ld; c += 64){ float v = p[c]; s += v * v; }
  #pragma unroll
  for (int o = 32; o; o >>= 1) s += __shfl_xor(s, o);
  if (!lane) sq[row] = s;
}

// ---------------------------------------------------------------------------
// NT GEMM: C[M,N] = A[M,K] @ Bt[N,K]^T (+bias, opt relu). bf16 in, f32 acc.
// OMODE 0: store bf16 C. 1: store bf16 + f32 C. 2: no store, accumulate
// sum((C - Xref)^2) into recAcc.
// ---------------------------------------------------------------------------
template<int BM, int BN, int WM, int WN, bool RELU, int OMODE>
__global__ __launch_bounds__(256, 2) void gemm_bt(
    const unsigned short* __restrict__ A, const unsigned short* __restrict__ Bt,
    const float* __restrict__ bias, int M, int N, int K,
    unsigned short* __restrict__ Cb, float* __restrict__ Cf,
    const float* __restrict__ Xref, float* __restrict__ recAcc)
{
  constexpr int FM = BM / (WM * 16), FN = BN / (WN * 16);
  __shared__ short As[BM][32];
  __shared__ short Bs[BN][32];
  __shared__ float wsum[4];
  const int tid = threadIdx.x, lane = tid & 63, wid = tid >> 6;
  const int wr = wid / WN, wc = wid % WN;
  const int r16 = lane & 15, kg = lane >> 4;
  const int row0 = blockIdx.x * BM, col0 = blockIdx.y * BN;
  const int srow = lane >> 2, scol = (lane & 3) * 8;   // staging: 16 rows/instr
  (void)M;
  f32x4 acc[FM][FN] = {};
  for (int k0 = 0; k0 < K; k0 += 32){
    __syncthreads();
    for (int ch = wid; ch < BM/16; ch += 4)
      gload16(A + (size_t)(row0 + ch*16 + srow) * K + k0 + scol, &As[ch*16][0]);
    for (int ch = wid; ch < BN/16; ch += 4)
      gload16(Bt + (size_t)(col0 + ch*16 + srow) * K + k0 + scol, &Bs[ch*16][0]);
    __syncthreads();
    bf16x8 af[FM], bfr[FN];
    #pragma unroll
    for (int m = 0; m < FM; m++) af[m]  = *(const bf16x8*)&As[wr*FM*16 + m*16 + r16][kg*8];
    #pragma unroll
    for (int n = 0; n < FN; n++) bfr[n] = *(const bf16x8*)&Bs[wc*FN*16 + n*16 + r16][kg*8];
    #pragma unroll
    for (int m = 0; m < FM; m++)
      #pragma unroll
      for (int n = 0; n < FN; n++)
        acc[m][n] = __builtin_amdgcn_mfma_f32_16x16x32_bf16(af[m], bfr[n], acc[m][n], 0, 0, 0);
  }
  float lsum = 0.f;
  #pragma unroll
  for (int m = 0; m < FM; m++){
    #pragma unroll
    for (int n = 0; n < FN; n++){
      const int gc = col0 + wc*FN*16 + n*16 + r16;
      const float bv = bias[gc];
      #pragma unroll
      for (int r = 0; r < 4; r++){
        const int gr = row0 + wr*FM*16 + m*16 + kg*4 + r;   // verified C/D map
        float v = acc[m][n][r] + bv;
        if (RELU) v = fmaxf(v, 0.f);
        if (OMODE == 2){
          float d = v - Xref[(size_t)gr * N + gc];
          lsum += d * d;
        } else {
          Cb[(size_t)gr * N + gc] = f2bf(v);
          if (OMODE == 1) Cf[(size_t)gr * N + gc] = v;
        }
      }
    }
  }
  if (OMODE == 2){
    #pragma unroll
    for (int o = 32; o; o >>= 1) lsum += __shfl_xor(lsum, o);
    if (!lane) wsum[wid] = lsum;
    __syncthreads();
    if (!tid) atomicAdd(recAcc, wsum[0] + wsum[1] + wsum[2] + wsum[3]);
  }
}

// ---------------------------------------------------------------------------
// Gram + streaming top-15. Block = 128 rows x 1024-j chunk (blockIdx.y of 8).
// Partial top-15 per (row, chunk) -> topvP/topjP [8192][8][15].
// ---------------------------------------------------------------------------
__global__ __launch_bounds__(256, 1) void gram_topk_k(
    const unsigned short* __restrict__ Xb, const float* __restrict__ xsq,
    float* __restrict__ topvP, int* __restrict__ topjP)
{
  __shared__ short As[128][32];
  __shared__ short Bs[128][32];
  __shared__ float d2[128][128];
  __shared__ float topv[128][15];
  __shared__ int   topj[128][15];
  __shared__ float thrS[128];
  __shared__ int   cntS[128];
  const int tid = threadIdx.x, lane = tid & 63, wid = tid >> 6;
  const int wr = wid >> 1, wc = wid & 1;
  const int r16 = lane & 15, kg = lane >> 4;
  const int row0 = blockIdx.x * 128;
  const int jbase = blockIdx.y * 1024;
  const int srow = lane >> 2, scol = (lane & 3) * 8;
  const float INF = __builtin_inff();
  if (tid < 128){ thrS[tid] = INF; cntS[tid] = 0; }
  for (int jt = 0; jt < 8; jt++){
    const int j0 = jbase + jt * 128;
    f32x4 acc[4][4] = {};
    for (int k0 = 0; k0 < 1024; k0 += 32){
      __syncthreads();
      for (int ch = wid; ch < 8; ch += 4){
        gload16(Xb + (size_t)(row0 + ch*16 + srow) * 1024 + k0 + scol, &As[ch*16][0]);
        gload16(Xb + (size_t)(j0   + ch*16 + srow) * 1024 + k0 + scol, &Bs[ch*16][0]);
      }
      __syncthreads();
      bf16x8 af[4], bfr[4];
      #pragma unroll
      for (int m = 0; m < 4; m++) af[m]  = *(const bf16x8*)&As[wr*64 + m*16 + r16][kg*8];
      #pragma unroll
      for (int n = 0; n < 4; n++) bfr[n] = *(const bf16x8*)&Bs[wc*64 + n*16 + r16][kg*8];
      #pragma unroll
      for (int m = 0; m < 4; m++)
        #pragma unroll
        for (int n = 0; n < 4; n++)
          acc[m][n] = __builtin_amdgcn_mfma_f32_16x16x32_bf16(af[m], bfr[n], acc[m][n], 0, 0, 0);
    }
    // d^2 tile (diag -> +inf)
    #pragma unroll
    for (int m = 0; m < 4; m++){
      #pragma unroll
      for (int n = 0; n < 4; n++){
        const int lc = wc*64 + n*16 + r16;
        const float xb2 = xsq[j0 + lc];
        #pragma unroll
        for (int r = 0; r < 4; r++){
          const int lr = wr*64 + m*16 + kg*4 + r;
          float v = xsq[row0 + lr] + xb2 - 2.f * acc[m][n][r];
          if (row0 + lr == j0 + lc) v = INF;
          d2[lr][lc] = v;
        }
      }
    }
    __syncthreads();
    // per-row top-15 merge; wave wid owns rows [wid*32, wid*32+32)
    for (int rr = 0; rr < 32; rr++){
      const int r = wid * 32 + rr;
      float T = thrS[r];
      int   C = cntS[r];
      float v0 = d2[r][lane], v1 = d2[r][64 + lane];
      const int jA = j0 + lane, jB = j0 + 64 + lane;
      bool changed = false;
      while (true){
        const bool c0 = v0 < T, c1 = v1 < T;
        if (!__any(c0 || c1)) break;            // fast path: no candidates
        changed = true;
        float mv; int mj;
        if (c0){ mv = v0; mj = jA; } else { mv = INF; mj = 0x7fffffff; }
        if (c1 && v1 < mv){ mv = v1; mj = jB; }
        #pragma unroll
        for (int o = 32; o; o >>= 1){
          float ov = __shfl_xor(mv, o); int oj = __shfl_xor(mj, o);
          if (ov < mv || (ov == mv && oj < mj)){ mv = ov; mj = oj; }
        }
        if (C < 15){
          if (!lane){ topv[r][C] = mv; topj[r][C] = mj; }
          C++;
          if (C == 15){
            float mx = mv;
            #pragma unroll
            for (int s = 0; s < 14; s++) mx = fmaxf(mx, topv[r][s]);
            T = mx;
          }
        } else {
          float mx = -INF; int sm = 0;
          #pragma unroll
          for (int s = 0; s < 15; s++){ float tv = topv[r][s]; if (tv > mx){ mx = tv; sm = s; } }
          if (!lane){ topv[r][sm] = mv; topj[r][sm] = mj; }
          float mx2 = mv;
          #pragma unroll
          for (int s = 0; s < 15; s++) if (s != sm) mx2 = fmaxf(mx2, topv[r][s]);
          T = mx2;
        }
        if (mj == jA) v0 = INF;
        if (mj == jB) v1 = INF;
      }
      if (changed && !lane){ thrS[r] = T; cntS[r] = C; }
    }
    __syncthreads();
  }
  for (int t = tid; t < 128 * 15; t += 256){
    const int r = t / 15, s = t % 15;
    const size_t o = ((size_t)(row0 + r) * 8 + blockIdx.y) * 15 + s;
    topvP[o] = topv[r][s];
    topjP[o] = topj[r][s];
  }
}

// merge 8 partial top-15 lists (120 candidates, unique j) -> final 15 per row
__global__ __launch_bounds__(256) void merge_topk_k(
    const float* __restrict__ topvP, const int* __restrict__ topjP,
    int* __restrict__ knn, float* __restrict__ d2k)
{
  const int lane = threadIdx.x & 63, wid = threadIdx.x >> 6;
  const int row = blockIdx.x * 4 + wid;
  const float INF = __builtin_inff();
  const float* vp = topvP + (size_t)row * 120;
  const int*   jp = topjP + (size_t)row * 120;
  float v0 = vp[lane];
  int   j0 = jp[lane];
  float v1 = (lane < 56) ? vp[lane + 64] : INF;
  int   j1 = (lane < 56) ? jp[lane + 64] : -1;
  for (int it = 0; it < 15; it++){
    float mv; int mj;
    if (v0 < v1 || (v0 == v1 && j0 < j1)){ mv = v0; mj = j0; } else { mv = v1; mj = j1; }
    #pragma unroll
    for (int o = 32; o; o >>= 1){
      float ov = __shfl_xor(mv, o); int oj = __shfl_xor(mj, o);
      if (ov < mv || (ov == mv && oj < mj)){ mv = ov; mj = oj; }
    }
    if (!lane){ knn[(size_t)row * 15 + it] = mj; d2k[(size_t)row * 15 + it] = mv; }
    if (mj == j0) v0 = INF;
    if (mj == j1) v1 = INF;
  }
}

__global__ void mask_build_k(const int* __restrict__ knn, unsigned* __restrict__ mask){
  int t = blockIdx.x * blockDim.x + threadIdx.x;
  if (t >= 8192 * 15) return;
  int i = t / 15, j = knn[t];
  atomicOr(&mask[i * 256 + (j >> 5)], 1u << (j & 31));
  atomicOr(&mask[j * 256 + (i >> 5)], 1u << (i & 31));
}

__global__ void gather_pairs_k(const unsigned* __restrict__ mask,
                               int2* __restrict__ pairs, int* __restrict__ count){
  int w = blockIdx.x * blockDim.x + threadIdx.x;
  if (w >= 8192 * 256) return;
  unsigned bits = mask[w];
  if (!bits) return;
  int i = w >> 8, base = (w & 255) << 5;
  int idx = atomicAdd(count, __popc(bits));
  while (bits){
    int b = __ffs(bits) - 1; bits &= bits - 1;
    pairs[idx++] = make_int2(i, base + b);
  }
}

// wave per pair: z-dist (64 dims, f32 z) + x-dist lookup from top-k values
__global__ __launch_bounds__(256) void pair_dist_k(
    const int2* __restrict__ pairs, const int* __restrict__ count,
    const float* __restrict__ z, const int* __restrict__ knn, const float* __restrict__ d2k,
    float* __restrict__ dxv, float* __restrict__ dzv,
    int* __restrict__ xmaxb, int* __restrict__ zmaxb)
{
  const int lane = threadIdx.x & 63;
  const int p = (int)((blockIdx.x * 256 + threadIdx.x) >> 6);
  if (p >= *count) return;
  const int2 pr = pairs[p];
  const int i = pr.x, j = pr.y;
  float d = z[(size_t)i * 64 + lane] - z[(size_t)j * 64 + lane];
  float s = d * d;
  #pragma unroll
  for (int o = 32; o; o >>= 1) s += __shfl_xor(s, o);
  int ki = knn[i * 15 + (lane % 15)];
  unsigned long long m1 = __ballot(lane < 15 && ki == j);
  float dx2 = 0.f;
  if (m1){
    dx2 = d2k[i * 15 + (__ffsll(m1) - 1)];
  } else {
    int kj = knn[j * 15 + (lane % 15)];
    unsigned long long m2 = __ballot(lane < 15 && kj == i);
    if (m2) dx2 = d2k[j * 15 + (__ffsll(m2) - 1)];
  }
  if (!lane){
    float dx = sqrtf(fmaxf(dx2, 0.f));
    float dz = sqrtf(fmaxf(s, 0.f));
    dxv[p] = dx; dzv[p] = dz;
    atomicMax(xmaxb, __float_as_int(dx));   // valid for nonneg floats
    atomicMax(zmaxb, __float_as_int(dz));
  }
}

__global__ __launch_bounds__(256) void knn_sum_k(
    const int* __restrict__ count, const float* __restrict__ dxv, const float* __restrict__ dzv,
    const int* __restrict__ xmaxb, const int* __restrict__ zmaxb, float* __restrict__ knnAcc)
{
  const int n = *count;
  const float rx = 1.0f / (__int_as_float(*xmaxb) + 1e-8f);
  const float rz = 1.0f / (__int_as_float(*zmaxb) + 1e-8f);
  float s = 0.f;
  for (int idx = blockIdx.x * 256 + threadIdx.x; idx < n; idx += gridDim.x * 256){
    float a = dzv[idx] * rz - dxv[idx] * rx;
    s += a * a;
  }
  #pragma unroll
  for (int o = 32; o; o >>= 1) s += __shfl_xor(s, o);
  __shared__ float wsum[4];
  const int lane = threadIdx.x & 63, wid = threadIdx.x >> 6;
  if (!lane) wsum[wid] = s;
  __syncthreads();
  if (!threadIdx.x) atomicAdd(knnAcc, wsum[0] + wsum[1] + wsum[2] + wsum[3]);
}

__global__ void finalize_k(const float* __restrict__ recAcc, const float* __restrict__ knnAcc,
                           const int* __restrict__ count, float* __restrict__ out){
  float rec = recAcc[0] * (1.0f / (8192.0f * 1024.0f));
  float knn = knnAcc[0] / (float)count[0];
  out[0] = rec + knn;                 // total
  out[1 + 8192 * 64]     = rec;       // rec_loss
  out[1 + 8192 * 64 + 1] = knn;       // knn_loss
}

// ===========================================================================
extern "C" void kernel_launch(void* const* d_in, const int* in_sizes, int n_in,
                              void* d_out, int out_size, void* d_ws, size_t ws_size,
                              hipStream_t stream)
{
  (void)in_sizes; (void)n_in; (void)out_size;
  const float* x    = (const float*)d_in[0];
  const float* w_e0 = (const float*)d_in[1];  const float* b_e0 = (const float*)d_in[2];
  const float* w_e1 = (const float*)d_in[3];  const float* b_e1 = (const float*)d_in[4];
  const float* w_e2 = (const float*)d_in[5];  const float* b_e2 = (const float*)d_in[6];
  const float* w_d0 = (const float*)d_in[7];  const float* b_d0 = (const float*)d_in[8];
  const float* w_d1 = (const float*)d_in[9];  const float* b_d1 = (const float*)d_in[10];
  const float* w_d2 = (const float*)d_in[11]; const float* b_d2 = (const float*)d_in[12];
  float* out = (float*)d_out;

  char* ws = (char*)d_ws;
  size_t off = 0;
  auto alloc = [&](size_t bytes) -> void* {
    void* p = ws + off;
    off += (bytes + 255) & ~(size_t)255;
    return p;
  };
  unsigned short* xb   = (unsigned short*)alloc(8192ull * 1024 * 2);
  unsigned short* wte0 = (unsigned short*)alloc(2048ull * 1024 * 2);
  unsigned short* wte1 = (unsigned short*)alloc(512ull  * 2048 * 2);
  unsigned short* wte2 = (unsigned short*)alloc(64ull   * 512  * 2);
  unsigned short* wtd0 = (unsigned short*)alloc(512ull  * 64   * 2);
  unsigned short* wtd1 = (unsigned short*)alloc(2048ull * 512  * 2);
  unsigned short* wtd2 = (unsigned short*)alloc(1024ull * 2048 * 2);
  unsigned short* bufA = (unsigned short*)alloc(8192ull * 2048 * 2);   // H1 / H4
  unsigned short* bufB = (unsigned short*)alloc(8192ull * 512  * 2);   // H2 / H3
  unsigned short* zb   = (unsigned short*)alloc(8192ull * 64   * 2);
  float* xsq   = (float*)alloc(8192 * 4);
  float* topvP = (float*)alloc(8192ull * 8 * 15 * 4);
  int*   topjP = (int*)  alloc(8192ull * 8 * 15 * 4);
  int*   knn   = (int*)  alloc(8192ull * 15 * 4);
  float* d2k   = (float*)alloc(8192ull * 15 * 4);
  unsigned* mask = (unsigned*)alloc(8192ull * 256 * 4);
  int2*  pairs = (int2*) alloc(245760ull * 8);
  float* dxv   = (float*)alloc(245760ull * 4);
  float* dzv   = (float*)alloc(245760ull * 4);
  char*  accs  = (char*) alloc(256);
  int*   count  = (int*)accs;
  int*   xmaxb  = (int*)(accs + 4);
  int*   zmaxb  = (int*)(accs + 8);
  float* recAcc = (float*)(accs + 12);
  float* knnAcc = (float*)(accs + 16);
  if (off > ws_size) return;   // fail loudly (poisoned output) rather than corrupt

  hipMemsetAsync(mask, 0, 8192ull * 256 * 4, stream);
  hipMemsetAsync(accs, 0, 256, stream);

  // --- conversions ---
  cvt_f32_bf16_k<<<8192, 256, 0, stream>>>(x, xb, 8192 * 1024 / 4);
  rowsq_k<<<2048, 256, 0, stream>>>(x, xsq, 1024);
  transpose_cvt_k<<<dim3(64, 32), dim3(32, 32), 0, stream>>>(w_e0, wte0, 1024, 2048);
  transpose_cvt_k<<<dim3(16, 64), dim3(32, 32), 0, stream>>>(w_e1, wte1, 2048, 512);
  transpose_cvt_k<<<dim3(2, 16),  dim3(32, 32), 0, stream>>>(w_e2, wte2, 512, 64);
  transpose_cvt_k<<<dim3(16, 2),  dim3(32, 32), 0, stream>>>(w_d0, wtd0, 64, 512);
  transpose_cvt_k<<<dim3(64, 16), dim3(32, 32), 0, stream>>>(w_d1, wtd1, 512, 2048);
  transpose_cvt_k<<<dim3(32, 64), dim3(32, 32), 0, stream>>>(w_d2, wtd2, 2048, 1024);

  // --- MLP ---
  gemm_bt<128,128,2,2,true ,0><<<dim3(64,16), 256, 0, stream>>>(xb,   wte0, b_e0, 8192, 2048, 1024, bufA, nullptr, nullptr, nullptr);
  gemm_bt<128,128,2,2,true ,0><<<dim3(64, 4), 256, 0, stream>>>(bufA, wte1, b_e1, 8192,  512, 2048, bufB, nullptr, nullptr, nullptr);
  gemm_bt< 64, 64,2,2,false,1><<<dim3(128,1), 256, 0, stream>>>(bufB, wte2, b_e2, 8192,   64,  512, zb,   out + 1, nullptr, nullptr);
  gemm_bt<128,128,2,2,true ,0><<<dim3(64, 4), 256, 0, stream>>>(zb,   wtd0, b_d0, 8192,  512,   64, bufB, nullptr, nullptr, nullptr);
  gemm_bt<128,128,2,2,true ,0><<<dim3(64,16), 256, 0, stream>>>(bufB, wtd1, b_d1, 8192, 2048,  512, bufA, nullptr, nullptr, nullptr);
  gemm_bt<128,128,2,2,false,2><<<dim3(64, 8), 256, 0, stream>>>(bufA, wtd2, b_d2, 8192, 1024, 2048, nullptr, nullptr, x, recAcc);

  // --- KNN ---
  gram_topk_k<<<dim3(64, 8), 256, 0, stream>>>(xb, xsq, topvP, topjP);
  merge_topk_k<<<2048, 256, 0, stream>>>(topvP, topjP, knn, d2k);
  mask_build_k<<<(8192 * 15 + 255) / 256, 256, 0, stream>>>(knn, mask);
  gather_pairs_k<<<8192, 256, 0, stream>>>(mask, pairs, count);
  pair_dist_k<<<61440, 256, 0, stream>>>(pairs, count, out + 1, knn, d2k, dxv, dzv, xmaxb, zmaxb);
  knn_sum_k<<<256, 256, 0, stream>>>(count, dxv, dzv, xmaxb, zmaxb, knnAcc);
  finalize_k<<<1, 1, 0, stream>>>(recAcc, knnAcc, count, out);
}

// Round 2
// 521.561 us; speedup vs baseline: 18.7919x; 18.7919x over previous
//
#include <hip/hip_runtime.h>

// ============================================================================
// MMAEKNN: MLP autoencoder fwd + rec_loss + KNN(15) loss, bf16 MFMA pipeline.
// R2: gram_topk redesigned (bf16-packed d2 in LDS, per-thread register top-15,
//     49.7KB LDS -> 2-3 blocks/CU); all same-address atomic storms replaced by
//     per-block partials + deterministic scan/compact + one final reduce.
// ============================================================================

typedef __attribute__((ext_vector_type(8))) short bf16x8;
typedef __attribute__((ext_vector_type(4))) float f32x4;

#define DEVINL static __device__ __forceinline__

DEVINL unsigned short f2bf(float f){
  unsigned u = __float_as_uint(f);
  u += 0x7FFFu + ((u >> 16) & 1u);              // round-to-nearest-even
  return (unsigned short)(u >> 16);
}

DEVINL int med3i(int a, int b, int c){
  return max(min(a, b), min(max(a, b), c));
}

DEVINL void gload16(const unsigned short* g, void* lds){
  __builtin_amdgcn_global_load_lds(
      (const __attribute__((address_space(1))) unsigned int*)g,
      (__attribute__((address_space(3))) unsigned int*)lds, 16, 0, 0);
}

// ---------------------------------------------------------------------------
__global__ __launch_bounds__(256) void cvt_f32_bf16_k(const float* __restrict__ in,
                                                      unsigned short* __restrict__ out, int n4){
  int i = blockIdx.x * 256 + threadIdx.x;
  if (i >= n4) return;
  float4 v = ((const float4*)in)[i];
  ushort4 o;
  o.x = f2bf(v.x); o.y = f2bf(v.y); o.z = f2bf(v.z); o.w = f2bf(v.w);
  ((ushort4*)out)[i] = o;
}

// w[K][N] f32 -> wt[N][K] bf16 (all dims multiples of 32)
__global__ void transpose_cvt_k(const float* __restrict__ w, unsigned short* __restrict__ wt,
                                int K, int N){
  __shared__ float t[32][33];
  int n0 = blockIdx.x << 5, k0 = blockIdx.y << 5;
  int tx = threadIdx.x, ty = threadIdx.y;
  t[ty][tx] = w[(size_t)(k0 + ty) * N + n0 + tx];
  __syncthreads();
  wt[(size_t)(n0 + ty) * K + k0 + tx] = f2bf(t[tx][ty]);
}

// row sums of squares (f32), one wave per row
__global__ __launch_bounds__(256) void rowsq_k(const float* __restrict__ x,
                                               float* __restrict__ sq, int ld){
  int lane = threadIdx.x & 63, wid = threadIdx.x >> 6;
  int row = blockIdx.x * 4 + wid;
  const float* p = x + (size_t)row * ld;
  float s = 0.f;
  for (int c = lane; c < ld; c += 64){ float v = p[c]; s += v * v; }
  #pragma unroll
  for (int o = 32; o; o >>= 1) s += __shfl_xor(s, o);
  if (!lane) sq[row] = s;
}

// ---------------------------------------------------------------------------
// NT GEMM: C[M,N] = A[M,K] @ Bt[N,K]^T (+bias, opt relu). bf16 in, f32 acc.
// OMODE 0: store bf16 C. 1: store bf16 + f32 C. 2: no store, per-block
// sum((C - Xref)^2) written to recPart[block].
// ---------------------------------------------------------------------------
template<int BM, int BN, int WM, int WN, bool RELU, int OMODE>
__global__ __launch_bounds__(256, 2) void gemm_bt(
    const unsigned short* __restrict__ A, const unsigned short* __restrict__ Bt,
    const float* __restrict__ bias, int M, int N, int K,
    unsigned short* __restrict__ Cb, float* __restrict__ Cf,
    const float* __restrict__ Xref, float* __restrict__ recPart)
{
  constexpr int FM = BM / (WM * 16), FN = BN / (WN * 16);
  __shared__ short As[BM][32];
  __shared__ short Bs[BN][32];
  __shared__ float wsum[4];
  const int tid = threadIdx.x, lane = tid & 63, wid = tid >> 6;
  const int wr = wid / WN, wc = wid % WN;
  const int r16 = lane & 15, kg = lane >> 4;
  const int row0 = blockIdx.x * BM, col0 = blockIdx.y * BN;
  const int srow = lane >> 2, scol = (lane & 3) * 8;   // staging: 16 rows/instr
  (void)M;
  f32x4 acc[FM][FN] = {};
  for (int k0 = 0; k0 < K; k0 += 32){
    __syncthreads();
    for (int ch = wid; ch < BM/16; ch += 4)
      gload16(A + (size_t)(row0 + ch*16 + srow) * K + k0 + scol, &As[ch*16][0]);
    for (int ch = wid; ch < BN/16; ch += 4)
      gload16(Bt + (size_t)(col0 + ch*16 + srow) * K + k0 + scol, &Bs[ch*16][0]);
    __syncthreads();
    bf16x8 af[FM], bfr[FN];
    #pragma unroll
    for (int m = 0; m < FM; m++) af[m]  = *(const bf16x8*)&As[wr*FM*16 + m*16 + r16][kg*8];
    #pragma unroll
    for (int n = 0; n < FN; n++) bfr[n] = *(const bf16x8*)&Bs[wc*FN*16 + n*16 + r16][kg*8];
    #pragma unroll
    for (int m = 0; m < FM; m++)
      #pragma unroll
      for (int n = 0; n < FN; n++)
        acc[m][n] = __builtin_amdgcn_mfma_f32_16x16x32_bf16(af[m], bfr[n], acc[m][n], 0, 0, 0);
  }
  float lsum = 0.f;
  #pragma unroll
  for (int m = 0; m < FM; m++){
    #pragma unroll
    for (int n = 0; n < FN; n++){
      const int gc = col0 + wc*FN*16 + n*16 + r16;
      const float bv = bias[gc];
      #pragma unroll
      for (int r = 0; r < 4; r++){
        const int gr = row0 + wr*FM*16 + m*16 + kg*4 + r;   // verified C/D map
        float v = acc[m][n][r] + bv;
        if (RELU) v = fmaxf(v, 0.f);
        if (OMODE == 2){
          float d = v - Xref[(size_t)gr * N + gc];
          lsum += d * d;
        } else {
          Cb[(size_t)gr * N + gc] = f2bf(v);
          if (OMODE == 1) Cf[(size_t)gr * N + gc] = v;
        }
      }
    }
  }
  if (OMODE == 2){
    #pragma unroll
    for (int o = 32; o; o >>= 1) lsum += __shfl_xor(lsum, o);
    if (!lane) wsum[wid] = lsum;
    __syncthreads();
    if (!tid) recPart[blockIdx.y * gridDim.x + blockIdx.x] =
        wsum[0] + wsum[1] + wsum[2] + wsum[3];
  }
}

// ---------------------------------------------------------------------------
// Gram + per-thread register top-15. Block = 128 rows x 1024-j chunk
// (blockIdx.y of 8), 8 tiles of 128x128 per block.
// d2 stored bf16 in LDS [128][130] (stride 130 ushorts: row-scan and frag
// writes both <=2-way bank conflict). Selection: thread t owns row t&127,
// col-half (t>>7)*64; keeps sorted top-15 packed (bf16val<<16 | j) in 15
// named regs; insert = guarded 15x med3 chain. Output: [8192][16][15] ints.
// ---------------------------------------------------------------------------
__global__ __launch_bounds__(256, 2) void gram_topk_k(
    const unsigned short* __restrict__ Xb, const float* __restrict__ xsq,
    int* __restrict__ topP)
{
  __shared__ short As[128][32];
  __shared__ short Bs[128][32];
  __shared__ unsigned short d2s[128][130];
  const int tid = threadIdx.x, lane = tid & 63, wid = tid >> 6;
  const int wr = wid >> 1, wc = wid & 1;
  const int r16 = lane & 15, kg = lane >> 4;
  const int row0 = blockIdx.x * 128;
  const int jbase = blockIdx.y * 1024;
  const int srow = lane >> 2, scol = (lane & 3) * 8;
  const float INF = __builtin_inff();

  const int selrow = tid & 127, selc0 = (tid >> 7) * 64;

  int r0,r1,r2,r3,r4,r5,r6,r7,r8,r9,r10,r11,r12,r13,r14;
  r0=r1=r2=r3=r4=r5=r6=r7=r8=r9=r10=r11=r12=r13=r14=0x7FFFFFFF;

  auto ins = [&](int v){
    if (v < r14){
      r14 = med3i(v, r13, r14);
      r13 = med3i(v, r12, r13);
      r12 = med3i(v, r11, r12);
      r11 = med3i(v, r10, r11);
      r10 = med3i(v, r9 , r10);
      r9  = med3i(v, r8 , r9 );
      r8  = med3i(v, r7 , r8 );
      r7  = med3i(v, r6 , r7 );
      r6  = med3i(v, r5 , r6 );
      r5  = med3i(v, r4 , r5 );
      r4  = med3i(v, r3 , r4 );
      r3  = med3i(v, r2 , r3 );
      r2  = med3i(v, r1 , r2 );
      r1  = med3i(v, r0 , r1 );
      r0  = min(r0, v);
    }
  };

  // row sums-of-squares for this wave's output rows (constant across tiles)
  float xr[4][4];
  #pragma unroll
  for (int m = 0; m < 4; m++)
    #pragma unroll
    for (int r = 0; r < 4; r++)
      xr[m][r] = xsq[row0 + wr*64 + m*16 + kg*4 + r];

  for (int jt = 0; jt < 8; jt++){
    const int j0 = jbase + jt * 128;
    f32x4 acc[4][4] = {};
    for (int k0 = 0; k0 < 1024; k0 += 32){
      __syncthreads();
      for (int ch = wid; ch < 8; ch += 4){
        gload16(Xb + (size_t)(row0 + ch*16 + srow) * 1024 + k0 + scol, &As[ch*16][0]);
        gload16(Xb + (size_t)(j0   + ch*16 + srow) * 1024 + k0 + scol, &Bs[ch*16][0]);
      }
      __syncthreads();
      bf16x8 af[4], bfr[4];
      #pragma unroll
      for (int m = 0; m < 4; m++) af[m]  = *(const bf16x8*)&As[wr*64 + m*16 + r16][kg*8];
      #pragma unroll
      for (int n = 0; n < 4; n++) bfr[n] = *(const bf16x8*)&Bs[wc*64 + n*16 + r16][kg*8];
      #pragma unroll
      for (int m = 0; m < 4; m++)
        #pragma unroll
        for (int n = 0; n < 4; n++)
          acc[m][n] = __builtin_amdgcn_mfma_f32_16x16x32_bf16(af[m], bfr[n], acc[m][n], 0, 0, 0);
    }
    // d^2 tile -> bf16 LDS (diag -> +inf)
    float xc[4];
    #pragma unroll
    for (int n = 0; n < 4; n++) xc[n] = xsq[j0 + wc*64 + n*16 + r16];
    #pragma unroll
    for (int m = 0; m < 4; m++){
      #pragma unroll
      for (int n = 0; n < 4; n++){
        const int lc = wc*64 + n*16 + r16;
        #pragma unroll
        for (int r = 0; r < 4; r++){
          const int lr = wr*64 + m*16 + kg*4 + r;
          float v = xr[m][r] + xc[n] - 2.f * acc[m][n][r];
          if (row0 + lr == j0 + lc) v = INF;
          d2s[lr][lc] = f2bf(v);
        }
      }
    }
    __syncthreads();
    // selection: 32 paired-column steps over this thread's row-half
    const int jg0 = jbase + jt * 128 + selc0;
    #pragma unroll 4
    for (int c2 = 0; c2 < 64; c2 += 2){
      unsigned pv = *(const unsigned*)&d2s[selrow][selc0 + c2];
      int p0 = (int)(((pv & 0xFFFFu) << 16) | (unsigned)(jg0 + c2));
      int p1 = (int)((pv & 0xFFFF0000u) | (unsigned)(jg0 + c2 + 1));
      ins(p0);
      ins(p1);
    }
    __syncthreads();
  }
  const int pbase = ((row0 + selrow) * 16 + blockIdx.y * 2 + (tid >> 7)) * 15;
  topP[pbase+ 0]=r0;  topP[pbase+ 1]=r1;  topP[pbase+ 2]=r2;  topP[pbase+ 3]=r3;
  topP[pbase+ 4]=r4;  topP[pbase+ 5]=r5;  topP[pbase+ 6]=r6;  topP[pbase+ 7]=r7;
  topP[pbase+ 8]=r8;  topP[pbase+ 9]=r9;  topP[pbase+10]=r10; topP[pbase+11]=r11;
  topP[pbase+12]=r12; topP[pbase+13]=r13; topP[pbase+14]=r14;
}

// merge 16 partial top-15 lists (240 unique-j candidates) -> final 15 per row.
// Also produces per-block max d2 (for x_max) in xpart[block] (no atomics).
__global__ __launch_bounds__(256) void merge_topk_k(const int* __restrict__ topP,
    int* __restrict__ knn, float* __restrict__ d2k, float* __restrict__ xpart)
{
  __shared__ float wmax[4];
  const int lane = threadIdx.x & 63, wid = threadIdx.x >> 6;
  const int row = blockIdx.x * 4 + wid;
  const int* tp = topP + (size_t)row * 240;
  int c0 = tp[lane];
  int c1 = tp[64 + lane];
  int c2 = tp[128 + lane];
  int c3 = (lane < 48) ? tp[192 + lane] : 0x7FFFFFFF;
  float last = 0.f;
  for (int it = 0; it < 15; it++){
    int m = min(min(c0, c1), min(c2, c3));
    #pragma unroll
    for (int o = 32; o; o >>= 1) m = min(m, __shfl_xor(m, o));
    if (!lane){
      knn[row * 15 + it] = m & 0xFFFF;
      float f = __uint_as_float((unsigned)m & 0xFFFF0000u);
      d2k[row * 15 + it] = f;
      last = f;
    }
    c0 = (c0 == m) ? 0x7FFFFFFF : c0;
    c1 = (c1 == m) ? 0x7FFFFFFF : c1;
    c2 = (c2 == m) ? 0x7FFFFFFF : c2;
    c3 = (c3 == m) ? 0x7FFFFFFF : c3;
  }
  if (!lane) wmax[wid] = last;
  __syncthreads();
  if (!threadIdx.x)
    xpart[blockIdx.x] = fmaxf(fmaxf(wmax[0], wmax[1]), fmaxf(wmax[2], wmax[3]));
}

__global__ void mask_build_k(const int* __restrict__ knn, unsigned* __restrict__ mask){
  int t = blockIdx.x * blockDim.x + threadIdx.x;
  if (t >= 8192 * 15) return;
  int i = t / 15, j = knn[t];
  atomicOr(&mask[i * 256 + (j >> 5)], 1u << (j & 31));
  atomicOr(&mask[j * 256 + (i >> 5)], 1u << (i & 31));
}

// per-row popcount of mask (wave per row)
__global__ __launch_bounds__(256) void rowcnt_k(const unsigned* __restrict__ mask,
                                                int* __restrict__ rowcnt){
  const int lane = threadIdx.x & 63, wid = threadIdx.x >> 6;
  const int row = blockIdx.x * 4 + wid;
  const unsigned* mr = mask + (size_t)row * 256;
  int pc = __popc(mr[lane]) + __popc(mr[64+lane]) + __popc(mr[128+lane]) + __popc(mr[192+lane]);
  #pragma unroll
  for (int o = 32; o; o >>= 1) pc += __shfl_xor(pc, o);
  if (!lane) rowcnt[row] = pc;
}

// single-block exclusive scan over 8192 row counts -> rowbase + total
__global__ __launch_bounds__(1024) void scan_k(const int* __restrict__ rowcnt,
                                               int* __restrict__ rowbase, int* __restrict__ count){
  __shared__ int sc[1024];
  const int t = threadIdx.x;
  int local[8];
  int s = 0;
  #pragma unroll
  for (int q = 0; q < 8; q++){ local[q] = s; s += rowcnt[t * 8 + q]; }
  sc[t] = s;
  __syncthreads();
  for (int o = 1; o < 1024; o <<= 1){
    int v = (t >= o) ? sc[t - o] : 0;
    __syncthreads();
    sc[t] += v;
    __syncthreads();
  }
  const int base = t ? sc[t - 1] : 0;
  #pragma unroll
  for (int q = 0; q < 8; q++) rowbase[t * 8 + q] = base + local[q];
  if (t == 1023) count[0] = sc[1023];
}

// deterministic compaction of set bits -> packed pairs (i<<16|j), wave per row
__global__ __launch_bounds__(256) void gather2_k(const unsigned* __restrict__ mask,
                                                 const int* __restrict__ rowbase,
                                                 unsigned* __restrict__ pairs){
  const int lane = threadIdx.x & 63, wid = threadIdx.x >> 6;
  const int row = blockIdx.x * 4 + wid;
  const unsigned* mr = mask + (size_t)row * 256;
  unsigned w0 = mr[lane], w1 = mr[64+lane], w2 = mr[128+lane], w3 = mr[192+lane];
  const int pc = __popc(w0) + __popc(w1) + __popc(w2) + __popc(w3);
  int s = pc;
  for (int o = 1; o < 64; o <<= 1){
    int v = __shfl_up(s, o);
    if (lane >= o) s += v;
  }
  int base = rowbase[row] + s - pc;
  const unsigned hi = (unsigned)row << 16;
  unsigned w; int jb;
  w = w0; jb = lane * 32;
  while (w){ int b = __ffs(w) - 1; w &= w - 1; pairs[base++] = hi | (unsigned)(jb + b); }
  w = w1; jb = (64 + lane) * 32;
  while (w){ int b = __ffs(w) - 1; w &= w - 1; pairs[base++] = hi | (unsigned)(jb + b); }
  w = w2; jb = (128 + lane) * 32;
  while (w){ int b = __ffs(w) - 1; w &= w - 1; pairs[base++] = hi | (unsigned)(jb + b); }
  w = w3; jb = (192 + lane) * 32;
  while (w){ int b = __ffs(w) - 1; w &= w - 1; pairs[base++] = hi | (unsigned)(jb + b); }
}

// per-pair z-dist + x-dist lookup; accumulate sum(dz^2), sum(dz*dx), sum(dx^2),
// max(dz) into per-block partials (expanded-form loss: no maxima needed here).
__global__ __launch_bounds__(256) void pair_sums_k(
    const unsigned* __restrict__ pairs, const int* __restrict__ count,
    const float* __restrict__ z, const int* __restrict__ knn, const float* __restrict__ d2k,
    float* __restrict__ zzP, float* __restrict__ zxP, float* __restrict__ xxP,
    float* __restrict__ zmP)
{
  __shared__ float red[4][4];
  const int lane = threadIdx.x & 63, wid = threadIdx.x >> 6;
  const int n = *count;
  float szz = 0.f, szx = 0.f, sxx = 0.f, mz = 0.f;
  for (int p = blockIdx.x * 4 + wid; p < n; p += gridDim.x * 4){
    const unsigned pr = pairs[p];
    const int i = (int)(pr >> 16), j = (int)(pr & 0xFFFFu);
    float d = z[i * 64 + lane] - z[j * 64 + lane];
    float s = d * d;
    #pragma unroll
    for (int o = 32; o; o >>= 1) s += __shfl_xor(s, o);
    int ki = knn[i * 15 + min(lane, 14)];
    unsigned long long m1 = __ballot(lane < 15 && ki == j);
    float dx2;
    if (m1){
      dx2 = d2k[i * 15 + (__ffsll(m1) - 1)];
    } else {
      int kj = knn[j * 15 + min(lane, 14)];
      unsigned long long m2 = __ballot(lane < 15 && kj == i);
      dx2 = d2k[j * 15 + (__ffsll(m2) - 1)];
    }
    float dz = sqrtf(s), dx = sqrtf(dx2);
    szz += s;
    szx += dz * dx;
    sxx += dx2;
    mz = fmaxf(mz, dz);
  }
  if (!lane){ red[wid][0] = szz; red[wid][1] = szx; red[wid][2] = sxx; red[wid][3] = mz; }
  __syncthreads();
  if (!threadIdx.x){
    float a = 0.f, b = 0.f, c = 0.f, m = 0.f;
    #pragma unroll
    for (int w = 0; w < 4; w++){
      a += red[w][0]; b += red[w][1]; c += red[w][2]; m = fmaxf(m, red[w][3]);
    }
    zzP[blockIdx.x] = a; zxP[blockIdx.x] = b; xxP[blockIdx.x] = c; zmP[blockIdx.x] = m;
  }
}

// single block: reduce all partials, compute losses, write outputs.
__global__ __launch_bounds__(256) void final_reduce_k(
    const float* __restrict__ recPart, const float* __restrict__ xpart,
    const float* __restrict__ zzP, const float* __restrict__ zxP,
    const float* __restrict__ xxP, const float* __restrict__ zmP,
    const int* __restrict__ count, float* __restrict__ out)
{
  __shared__ float rd[4][6];
  const int t = threadIdx.x, lane = t & 63, wid = t >> 6;
  float rec = 0.f, xm = 0.f, zz = 0.f, zx = 0.f, xx = 0.f, zm = 0.f;
  for (int i = t; i < 512; i += 256) rec += recPart[i];
  for (int i = t; i < 2048; i += 256) xm = fmaxf(xm, xpart[i]);
  for (int i = t; i < 1920; i += 256){
    zz += zzP[i]; zx += zxP[i]; xx += xxP[i]; zm = fmaxf(zm, zmP[i]);
  }
  #pragma unroll
  for (int o = 32; o; o >>= 1){
    rec += __shfl_xor(rec, o); zz += __shfl_xor(zz, o);
    zx  += __shfl_xor(zx, o);  xx += __shfl_xor(xx, o);
    xm = fmaxf(xm, __shfl_xor(xm, o));
    zm = fmaxf(zm, __shfl_xor(zm, o));
  }
  if (!lane){
    rd[wid][0]=rec; rd[wid][1]=zz; rd[wid][2]=zx; rd[wid][3]=xx; rd[wid][4]=xm; rd[wid][5]=zm;
  }
  __syncthreads();
  if (!t){
    rec = rd[0][0]+rd[1][0]+rd[2][0]+rd[3][0];
    zz  = rd[0][1]+rd[1][1]+rd[2][1]+rd[3][1];
    zx  = rd[0][2]+rd[1][2]+rd[2][2]+rd[3][2];
    xx  = rd[0][3]+rd[1][3]+rd[2][3]+rd[3][3];
    xm  = fmaxf(fmaxf(rd[0][4],rd[1][4]), fmaxf(rd[2][4],rd[3][4]));
    zm  = fmaxf(fmaxf(rd[0][5],rd[1][5]), fmaxf(rd[2][5],rd[3][5]));
    rec *= 1.0f / (8192.0f * 1024.0f);
    float xmax = sqrtf(xm);
    float rx = 1.0f / (xmax + 1e-8f), rz = 1.0f / (zm + 1e-8f);
    float knn = (zz * rz * rz - 2.0f * zx * rz * rx + xx * rx * rx) / (float)count[0];
    out[0] = rec + knn;                 // total
    out[1 + 8192 * 64]     = rec;       // rec_loss
    out[1 + 8192 * 64 + 1] = knn;       // knn_loss
  }
}

// ===========================================================================
extern "C" void kernel_launch(void* const* d_in, const int* in_sizes, int n_in,
                              void* d_out, int out_size, void* d_ws, size_t ws_size,
                              hipStream_t stream)
{
  (void)in_sizes; (void)n_in; (void)out_size;
  const float* x    = (const float*)d_in[0];
  const float* w_e0 = (const float*)d_in[1];  const float* b_e0 = (const float*)d_in[2];
  const float* w_e1 = (const float*)d_in[3];  const float* b_e1 = (const float*)d_in[4];
  const float* w_e2 = (const float*)d_in[5];  const float* b_e2 = (const float*)d_in[6];
  const float* w_d0 = (const float*)d_in[7];  const float* b_d0 = (const float*)d_in[8];
  const float* w_d1 = (const float*)d_in[9];  const float* b_d1 = (const float*)d_in[10];
  const float* w_d2 = (const float*)d_in[11]; const float* b_d2 = (const float*)d_in[12];
  float* out = (float*)d_out;

  char* ws = (char*)d_ws;
  size_t off = 0;
  auto alloc = [&](size_t bytes) -> void* {
    void* p = ws + off;
    off += (bytes + 255) & ~(size_t)255;
    return p;
  };
  unsigned short* xb   = (unsigned short*)alloc(8192ull * 1024 * 2);
  unsigned short* wte0 = (unsigned short*)alloc(2048ull * 1024 * 2);
  unsigned short* wte1 = (unsigned short*)alloc(512ull  * 2048 * 2);
  unsigned short* wte2 = (unsigned short*)alloc(64ull   * 512  * 2);
  unsigned short* wtd0 = (unsigned short*)alloc(512ull  * 64   * 2);
  unsigned short* wtd1 = (unsigned short*)alloc(2048ull * 512  * 2);
  unsigned short* wtd2 = (unsigned short*)alloc(1024ull * 2048 * 2);
  unsigned short* bufA = (unsigned short*)alloc(8192ull * 2048 * 2);   // H1 / H4
  unsigned short* bufB = (unsigned short*)alloc(8192ull * 512  * 2);   // H2 / H3
  unsigned short* zb   = (unsigned short*)alloc(8192ull * 64   * 2);
  float* xsq    = (float*)alloc(8192 * 4);
  int*   topP   = (int*)  alloc(8192ull * 240 * 4);
  int*   knn    = (int*)  alloc(8192ull * 15 * 4);
  float* d2k    = (float*)alloc(8192ull * 15 * 4);
  unsigned* mask = (unsigned*)alloc(8192ull * 256 * 4);
  int*   rowcnt = (int*)  alloc(8192 * 4);
  int*   rowbase= (int*)  alloc(8192 * 4);
  unsigned* pairs = (unsigned*)alloc(245760ull * 4);
  float* xpart  = (float*)alloc(2048 * 4);
  float* zzP    = (float*)alloc(1920 * 4);
  float* zxP    = (float*)alloc(1920 * 4);
  float* xxP    = (float*)alloc(1920 * 4);
  float* zmP    = (float*)alloc(1920 * 4);
  float* recPart= (float*)alloc(512 * 4);
  int*   count  = (int*)  alloc(256);
  if (off > ws_size) return;   // fail loudly (poisoned output) rather than corrupt

  hipMemsetAsync(mask, 0, 8192ull * 256 * 4, stream);

  // --- conversions ---
  cvt_f32_bf16_k<<<8192, 256, 0, stream>>>(x, xb, 8192 * 1024 / 4);
  rowsq_k<<<2048, 256, 0, stream>>>(x, xsq, 1024);
  transpose_cvt_k<<<dim3(64, 32), dim3(32, 32), 0, stream>>>(w_e0, wte0, 1024, 2048);
  transpose_cvt_k<<<dim3(16, 64), dim3(32, 32), 0, stream>>>(w_e1, wte1, 2048, 512);
  transpose_cvt_k<<<dim3(2, 16),  dim3(32, 32), 0, stream>>>(w_e2, wte2, 512, 64);
  transpose_cvt_k<<<dim3(16, 2),  dim3(32, 32), 0, stream>>>(w_d0, wtd0, 64, 512);
  transpose_cvt_k<<<dim3(64, 16), dim3(32, 32), 0, stream>>>(w_d1, wtd1, 512, 2048);
  transpose_cvt_k<<<dim3(32, 64), dim3(32, 32), 0, stream>>>(w_d2, wtd2, 2048, 1024);

  // --- MLP ---
  gemm_bt<128,128,2,2,true ,0><<<dim3(64,16), 256, 0, stream>>>(xb,   wte0, b_e0, 8192, 2048, 1024, bufA, nullptr, nullptr, nullptr);
  gemm_bt<128,128,2,2,true ,0><<<dim3(64, 4), 256, 0, stream>>>(bufA, wte1, b_e1, 8192,  512, 2048, bufB, nullptr, nullptr, nullptr);
  gemm_bt< 64, 64,2,2,false,1><<<dim3(128,1), 256, 0, stream>>>(bufB, wte2, b_e2, 8192,   64,  512, zb,   out + 1, nullptr, nullptr);
  gemm_bt<128,128,2,2,true ,0><<<dim3(64, 4), 256, 0, stream>>>(zb,   wtd0, b_d0, 8192,  512,   64, bufB, nullptr, nullptr, nullptr);
  gemm_bt<128,128,2,2,true ,0><<<dim3(64,16), 256, 0, stream>>>(bufB, wtd1, b_d1, 8192, 2048,  512, bufA, nullptr, nullptr, nullptr);
  gemm_bt<128,128,2,2,false,2><<<dim3(64, 8), 256, 0, stream>>>(bufA, wtd2, b_d2, 8192, 1024, 2048, nullptr, nullptr, x, recPart);

  // --- KNN ---
  gram_topk_k<<<dim3(64, 8), 256, 0, stream>>>(xb, xsq, topP);
  merge_topk_k<<<2048, 256, 0, stream>>>(topP, knn, d2k, xpart);
  mask_build_k<<<(8192 * 15 + 255) / 256, 256, 0, stream>>>(knn, mask);
  rowcnt_k<<<2048, 256, 0, stream>>>(mask, rowcnt);
  scan_k<<<1, 1024, 0, stream>>>(rowcnt, rowbase, count);
  gather2_k<<<2048, 256, 0, stream>>>(mask, rowbase, pairs);
  pair_sums_k<<<1920, 256, 0, stream>>>(pairs, count, out + 1, knn, d2k, zzP, zxP, xxP, zmP);
  final_reduce_k<<<1, 256, 0, stream>>>(recPart, xpart, zzP, zxP, xxP, zmP, count, out);
}